// Round 9
// baseline (438.610 us; speedup 1.0000x reference)
//
#include <hip/hip_runtime.h>
#include <hip/hip_bf16.h>
#include <math.h>

// B=2, S=2048, H=2048, NH=16, HD=128
#define SEQ 2048
#define HID 2048
#define NHEAD 16
#define HDIM 128
#define LDK 4096   // fused QK row stride

typedef __bf16 bf16_t;
typedef __bf16 bf16x2 __attribute__((ext_vector_type(2)));
typedef __bf16 bf16x4_t __attribute__((ext_vector_type(4)));
typedef __bf16 bf16x8 __attribute__((ext_vector_type(8)));
typedef float f32x4 __attribute__((ext_vector_type(4)));
typedef float f32x16 __attribute__((ext_vector_type(16)));
typedef unsigned u32x4 __attribute__((ext_vector_type(4)));

#define MFMA16(a, b, c) __builtin_amdgcn_mfma_f32_16x16x32_bf16(a, b, c, 0, 0, 0)
#define MFMA32(a, b, c) __builtin_amdgcn_mfma_f32_32x32x16_bf16(a, b, c, 0, 0, 0)
#define GLOAD_LDS(g, l) \
  __builtin_amdgcn_global_load_lds((const __attribute__((address_space(1))) void*)(g), \
                                   (__attribute__((address_space(3))) void*)(l), 16, 0, 0)

static __device__ inline unsigned pk2(float lo, float hi) {
  bf16x2 t; t[0] = (bf16_t)lo; t[1] = (bf16_t)hi;
  return __builtin_bit_cast(unsigned, t);
}

// pack 8 p-values (one 16-key slice) into the PV B-fragment via cross-half exchange
static __device__ inline bf16x8 pack_slice(const float* p, int hi) {
  unsigned A1 = pk2(p[0], p[1]);
  unsigned A2 = pk2(p[2], p[3]);
  unsigned B1 = pk2(p[4], p[5]);
  unsigned B2 = pk2(p[6], p[7]);
  unsigned A1s = __shfl_xor(A1, 32, 64);
  unsigned A2s = __shfl_xor(A2, 32, 64);
  unsigned B1s = __shfl_xor(B1, 32, 64);
  unsigned B2s = __shfl_xor(B2, 32, 64);
  unsigned w0 = hi ? B1s : A1;
  unsigned w1 = hi ? B2s : A2;
  unsigned w2 = hi ? B1 : A1s;
  unsigned w3 = hi ? B2 : A2s;
  u32x4 W = {w0, w1, w2, w3};
  return __builtin_bit_cast(bf16x8, W);
}

// ---------------- cast kernels ----------------
__global__ void cast_hidden(const float* __restrict__ in, bf16_t* __restrict__ out) {
  int i = blockIdx.x * 256 + threadIdx.x;
  float4 v = ((const float4*)in)[i];
  bf16x4_t b;
  b[0] = (bf16_t)v.x; b[1] = (bf16_t)v.y; b[2] = (bf16_t)v.z; b[3] = (bf16_t)v.w;
  ((bf16x4_t*)out)[i] = b;
}

__global__ void cast_weights(const float* __restrict__ a, const float* __restrict__ b,
                             const float* __restrict__ c, const float* __restrict__ d,
                             bf16_t* __restrict__ out) {
  const float* srcs[4] = {a, b, c, d};
  const float* src = srcs[blockIdx.y];
  bf16_t* dst = out + (size_t)blockIdx.y * (HID * HID);
  int i = blockIdx.x * 256 + threadIdx.x;
  float4 v = ((const float4*)src)[i];
  bf16x4_t o;
  o[0] = (bf16_t)v.x; o[1] = (bf16_t)v.y; o[2] = (bf16_t)v.z; o[3] = (bf16_t)v.w;
  ((bf16x4_t*)dst)[i] = o;
}

// ---------------- 256x256 8-phase GEMM (grid MUST be 256 = 16x16 tiles) ----------
__global__ __launch_bounds__(512, 2) void gemm256(
    const bf16_t* __restrict__ A, const bf16_t* __restrict__ Bw,
    bf16_t* __restrict__ Cb, float* __restrict__ Cf, int M, int N, int K) {
  __shared__ char smem[131072];
  const int tid = threadIdx.x, lane = tid & 63, wid = tid >> 6;
  const int wr = wid >> 2, wc = wid & 3;
  const int lr = lane & 15, lg = lane >> 4;
  const int xcd = blockIdx.x & 7, l = blockIdx.x >> 3;
  const int brow = (xcd >> 2) * 8 + (l >> 2);
  const int bcol = (xcd & 3) * 4 + (l & 3);
  const int NT = K >> 6;

  const bf16_t* Ab = A + (size_t)(brow * 256) * K;
  const bf16_t* Bb = Bw + (size_t)(bcol * 256) * K;

  f32x4 acc[8][4] = {};
  bf16x8 af[4], bfr[4];
  const int swz = (lg ^ ((lr >> 1) & 3)) << 4;

#define STAGE_HALF(t_, op, kh)                                                        \
  {                                                                                   \
    int tt = (t_) < NT ? (t_) : NT - 1;                                               \
    const bf16_t* gsrc = (op) ? Bb : Ab;                                              \
    char* ldst = smem + (tt & 1) * 65536 + (op) * 32768 + (kh) * 16384;               \
    _Pragma("unroll") for (int is = 0; is < 2; ++is) {                                \
      int p = tid + is * 512;                                                         \
      int row = p >> 2, ch = p & 3;                                                   \
      GLOAD_LDS(gsrc + (size_t)row * K + tt * 64 + (kh) * 32 +                        \
                    ((ch ^ ((row >> 1) & 3)) * 8),                                    \
                ldst + p * 16);                                                       \
    }                                                                                 \
  }

#define PHASE(cb, kh, mh, LOADB, STAGECALL, VM)                                       \
  {                                                                                   \
    _Pragma("unroll") for (int mf = 0; mf < 4; ++mf) {                                \
      int row = wr * 128 + (mh) * 64 + mf * 16 + lr;                                  \
      af[mf] = *(const bf16x8*)(smem + (cb) * 65536 + (kh) * 16384 + row * 64 + swz); \
    }                                                                                 \
    if (LOADB) {                                                                      \
      _Pragma("unroll") for (int nf = 0; nf < 4; ++nf) {                              \
        int row = wc * 64 + nf * 16 + lr;                                             \
        bfr[nf] = *(const bf16x8*)(smem + (cb) * 65536 + 32768 + (kh) * 16384 +       \
                                   row * 64 + swz);                                   \
      }                                                                               \
    }                                                                                 \
    STAGECALL;                                                                        \
    __builtin_amdgcn_s_barrier();                                                     \
    asm volatile("s_waitcnt lgkmcnt(0)" ::: "memory");                                \
    __builtin_amdgcn_sched_barrier(0);                                                \
    __builtin_amdgcn_s_setprio(1);                                                    \
    _Pragma("unroll") for (int mf = 0; mf < 4; ++mf)                                  \
      _Pragma("unroll") for (int nf = 0; nf < 4; ++nf)                                \
        acc[(mh) * 4 + mf][nf] = MFMA16(af[mf], bfr[nf], acc[(mh) * 4 + mf][nf]);     \
    __builtin_amdgcn_s_setprio(0);                                                    \
    if (VM) { asm volatile("s_waitcnt vmcnt(6)" ::: "memory"); }                      \
    __builtin_amdgcn_s_barrier();                                                     \
    __builtin_amdgcn_sched_barrier(0);                                                \
  }

  STAGE_HALF(0, 1, 0); STAGE_HALF(0, 0, 0); STAGE_HALF(0, 1, 1); STAGE_HALF(0, 0, 1);
  STAGE_HALF(1, 1, 0); STAGE_HALF(1, 0, 0); STAGE_HALF(1, 1, 1);
  asm volatile("s_waitcnt vmcnt(6)" ::: "memory");
  __builtin_amdgcn_s_barrier();
  __builtin_amdgcn_sched_barrier(0);

  const int NI = NT >> 1;
  for (int i = 0; i < NI; ++i) {
    const int t2 = 2 * i;
    PHASE(0, 0, 0, 1, STAGE_HALF(t2 + 1, 0, 1), 0);
    PHASE(0, 0, 1, 0, STAGE_HALF(t2 + 2, 1, 0), 0);
    PHASE(0, 1, 0, 1, STAGE_HALF(t2 + 2, 0, 0), 0);
    PHASE(0, 1, 1, 0, STAGE_HALF(t2 + 2, 1, 1), 1);
    PHASE(1, 0, 0, 1, STAGE_HALF(t2 + 2, 0, 1), 0);
    PHASE(1, 0, 1, 0, STAGE_HALF(t2 + 3, 1, 0), 0);
    PHASE(1, 1, 0, 1, STAGE_HALF(t2 + 3, 0, 0), 0);
    PHASE(1, 1, 1, 0, STAGE_HALF(t2 + 3, 1, 1), 1);
  }
#undef PHASE
#undef STAGE_HALF

#pragma unroll
  for (int mi = 0; mi < 8; ++mi)
#pragma unroll
    for (int nf = 0; nf < 4; ++nf)
#pragma unroll
      for (int r = 0; r < 4; ++r) {
        int row = brow * 256 + wr * 128 + (mi >> 2) * 64 + (mi & 3) * 16 + lg * 4 + r;
        int col = bcol * 256 + wc * 64 + nf * 16 + lr;
        float v = acc[mi][nf][r];
        if (Cf) Cf[(size_t)row * N + col] = v;
        else    Cb[(size_t)row * N + col] = (bf16_t)v;
      }
}

// ---------------- GEMM: C = A * B^T, 2-phase double-buffered (128x128) -------------
__global__ __launch_bounds__(256, 3) void gemm_bt(
    const bf16_t* __restrict__ A, const bf16_t* __restrict__ Bw,
    bf16_t* __restrict__ Cb, float* __restrict__ Cf,
    int M, int N, int K) {
  __shared__ bf16_t As[2][128 * 32];
  __shared__ bf16_t Bs[2][128 * 32];
  const int tid = threadIdx.x;
  const int lane = tid & 63, wid = tid >> 6;
  const int wr = wid >> 1, wc = wid & 1;
  const int lr = lane & 15, lg = lane >> 4;
  const int nwg = gridDim.x;
  const int lid = (blockIdx.x & 7) * (nwg >> 3) + (blockIdx.x >> 3);
  const int nbc = N >> 7;
  const int brow = lid / nbc, bcol = lid % nbc;

  f32x4 acc[4][4] = {};
  const int swz = lg ^ ((lr >> 1) & 3);

  const int srow = tid >> 2, sch = tid & 3;
#define GSTAGE(k0, bb)                                                                   \
  {                                                                                      \
    _Pragma("unroll") for (int is = 0; is < 2; ++is) {                                   \
      int row = srow + is * 64;                                                          \
      int g = (sch ^ ((row >> 1) & 3)) * 8;                                              \
      GLOAD_LDS(A + (size_t)(brow * 128 + row) * K + (k0) + g,                           \
                &As[bb][(row * 4 + sch) * 8]);                                           \
      GLOAD_LDS(Bw + (size_t)(bcol * 128 + row) * K + (k0) + g,                          \
                &Bs[bb][(row * 4 + sch) * 8]);                                           \
    }                                                                                    \
  }

  GSTAGE(0, 0);
  __syncthreads();

  const int nt = K / 32;
  for (int t = 0; t < nt; ++t) {
    const int cb = t & 1;
    if (t + 1 < nt) GSTAGE((t + 1) * 32, cb ^ 1);
    bf16x8 af[4], bfr[4];
#pragma unroll
    for (int m = 0; m < 4; ++m)
      af[m] = *(const bf16x8*)(&As[cb][(wr * 64 + m * 16 + lr) * 32 + swz * 8]);
#pragma unroll
    for (int n = 0; n < 4; ++n)
      bfr[n] = *(const bf16x8*)(&Bs[cb][(wc * 64 + n * 16 + lr) * 32 + swz * 8]);
#pragma unroll
    for (int m = 0; m < 4; ++m)
#pragma unroll
      for (int n = 0; n < 4; ++n)
        acc[m][n] = MFMA16(af[m], bfr[n], acc[m][n]);
    __syncthreads();
  }
#undef GSTAGE

#pragma unroll
  for (int m = 0; m < 4; ++m)
#pragma unroll
    for (int n = 0; n < 4; ++n)
#pragma unroll
      for (int r = 0; r < 4; ++r) {
        int row = brow * 128 + wr * 64 + m * 16 + lg * 4 + r;
        int col = bcol * 128 + wc * 64 + n * 16 + lr;
        float v = acc[m][n][r];
        if (Cf) Cf[(size_t)row * N + col] = v;
        else    Cb[(size_t)row * N + col] = (bf16_t)v;
      }
}

// ---------------- RoPE in-place on QK buffer (stride LDK); Q pre-scaled ----------
__global__ void rope_qk(bf16_t* __restrict__ QK,
                        const float* __restrict__ cost, const float* __restrict__ sint) {
  const float SCALE = 0.08838834764831845f;  // 1/sqrt(128)
  int idx = blockIdx.x * 256 + threadIdx.x;
  int d8 = idx & 7;
  int t = idx >> 3;
  int h = t & 15;
  int row = t >> 4;
  int s = row & (SEQ - 1);
  size_t base = (size_t)row * LDK + h * HDIM;
  const float4* cp = (const float4*)(cost + s * HDIM);
  const float4* sp = (const float4*)(sint + s * HDIM);
  float4 c0a = cp[d8 * 2], c0b = cp[d8 * 2 + 1];
  float4 c1a = cp[16 + d8 * 2], c1b = cp[16 + d8 * 2 + 1];
  float4 s0a = sp[d8 * 2], s0b = sp[d8 * 2 + 1];
  float4 s1a = sp[16 + d8 * 2], s1b = sp[16 + d8 * 2 + 1];
  float c0[8] = {c0a.x, c0a.y, c0a.z, c0a.w, c0b.x, c0b.y, c0b.z, c0b.w};
  float c1[8] = {c1a.x, c1a.y, c1a.z, c1a.w, c1b.x, c1b.y, c1b.z, c1b.w};
  float s0[8] = {s0a.x, s0a.y, s0a.z, s0a.w, s0b.x, s0b.y, s0b.z, s0b.w};
  float s1[8] = {s1a.x, s1a.y, s1a.z, s1a.w, s1b.x, s1b.y, s1b.z, s1b.w};

  bf16_t* Q = QK;
  bf16_t* K = QK + 2048;
  bf16x8 qlo = *(bf16x8*)(Q + base + d8 * 8);
  bf16x8 qhi = *(bf16x8*)(Q + base + 64 + d8 * 8);
  bf16x8 klo = *(bf16x8*)(K + base + d8 * 8);
  bf16x8 khi = *(bf16x8*)(K + base + 64 + d8 * 8);
  bf16x8 qlo2, qhi2, klo2, khi2;
#pragma unroll
  for (int j = 0; j < 8; ++j) {
    float q0 = (float)qlo[j], q1 = (float)qhi[j];
    qlo2[j] = (bf16_t)((q0 * c0[j] - q1 * s0[j]) * SCALE);
    qhi2[j] = (bf16_t)((q1 * c1[j] + q0 * s1[j]) * SCALE);
    float k0 = (float)klo[j], k1 = (float)khi[j];
    klo2[j] = (bf16_t)(k0 * c0[j] - k1 * s0[j]);
    khi2[j] = (bf16_t)(k1 * c1[j] + k0 * s1[j]);
  }
  *(bf16x8*)(Q + base + d8 * 8) = qlo2;
  *(bf16x8*)(Q + base + 64 + d8 * 8) = qhi2;
  *(bf16x8*)(K + base + d8 * 8) = klo2;
  *(bf16x8*)(K + base + 64 + d8 * 8) = khi2;
}

// ---------------- V transpose: Vf (B*S x H) -> Vt[b][h][d][s] ----------------
__global__ void transpose_v(const bf16_t* __restrict__ Vf, bf16_t* __restrict__ Vt) {
  __shared__ bf16_t t[32][33];
  int tx = threadIdx.x & 31, ty = threadIdx.x >> 5;
  int r0 = blockIdx.y * 32, c0 = blockIdx.x * 32;
#pragma unroll
  for (int j = 0; j < 4; ++j)
    t[ty + j * 8][tx] = Vf[(size_t)(r0 + ty + j * 8) * HID + c0 + tx];
  __syncthreads();
#pragma unroll
  for (int j = 0; j < 4; ++j) {
    int c = c0 + ty + j * 8;
    int r = r0 + tx;
    int h = c >> 7, d = c & 127, b = r >> 11, s = r & (SEQ - 1);
    Vt[(((size_t)(b * NHEAD + h)) * HDIM + d) * SEQ + s] = t[tx][ty + j * 8];
  }
}

// ---------------- mask pack: mask[b][0][q][k] f32 -> maskP[b][kg][q][kl'] bf16 ------
__global__ void mask_pack(const float* __restrict__ m, bf16_t* __restrict__ mp) {
  __shared__ float t[32][33];
  int tx = threadIdx.x & 31, ty = threadIdx.x >> 5;
  int q0 = blockIdx.x * 32, k0 = blockIdx.y * 32;
  const float* mb = m + (size_t)blockIdx.z * SEQ * SEQ;
#pragma unroll
  for (int j = 0; j < 4; ++j)
    t[ty + j * 8][tx] = mb[(size_t)(q0 + ty + j * 8) * SEQ + k0 + tx];
  __syncthreads();
  int r = tx & 15, hi = tx >> 4;
  int kl = (r & 3) + 8 * (r >> 2) + 4 * hi;
  bf16_t* ob = mp + ((size_t)(blockIdx.z * 64 + blockIdx.y) * 2048 + q0) * 32;
#pragma unroll
  for (int j = 0; j < 4; ++j) {
    int qloc = ty + j * 8;
    ob[(size_t)qloc * 32 + tx] = (bf16_t)t[qloc][kl];
  }
}

// ---------------- flash attention fwd v4: split-K, 64 q/wave, conflict-free LDS -----
// grid 512 = 2 key-halves x 8 qt x 32 bh -> 2 blocks/CU (8 waves/CU).
// 4 waves x 64 q = 256 q/block; KVBLK=64 double-buffered (64 KB LDS).
// K tile [64 keys][256B], (row&15) XOR.  V tile pair-interleaved: row r holds
// d=2r (128B) | d=2r+1 (128B) -> 256B rows, same conflict-free pattern.
// Emits unnormalized partial O (bf16) + (m, l) per q-row; combine() merges halves.
__global__ __launch_bounds__(256, 2) void flash_fwd(
    const bf16_t* __restrict__ Qf, const bf16_t* __restrict__ Kf,
    const bf16_t* __restrict__ Vt, const bf16_t* __restrict__ maskP,
    bf16_t* __restrict__ Op0, bf16_t* __restrict__ Op1, float2* __restrict__ ml) {
  __shared__ char smem[65536];           // K 2x16K | V 2x16K
  char* KsB = smem;
  char* VsB = smem + 32768;
  const int tid = threadIdx.x, lane = tid & 63, wid = tid >> 6;
  const int q32 = lane & 31, hi = lane >> 5;

  // XCD swizzle: each XCD owns 4 bh values (L2-resident K/V working set ~4MB)
  const int lid = (blockIdx.x & 7) * 64 + (blockIdx.x >> 3);
  const int bh = lid >> 4, kh = (lid >> 3) & 1, qt = lid & 7;
  const int b = bh >> 4, h = bh & 15;
  const int qg0 = qt * 256 + wid * 64 + q32;   // q-group 0; group 1 = +32
  const int kbase = kh * 1024;

  // Q fragments for both q-groups
  bf16x8 qf0[8], qf1[8];
  const bf16_t* qp0 = Qf + (size_t)(b * SEQ + qg0) * LDK + h * HDIM + hi * 8;
  const bf16_t* qp1 = qp0 + (size_t)32 * LDK;
#pragma unroll
  for (int ds = 0; ds < 8; ++ds) {
    qf0[ds] = *(const bf16x8*)(qp0 + ds * 16);
    qf1[ds] = *(const bf16x8*)(qp1 + ds * 16);
  }

  const bf16_t* mQ0 = maskP + (size_t)b * 64 * 65536 + (size_t)qg0 * 32 + hi * 16;
  const bf16_t* mQ1 = mQ0 + 32 * 32;

  float mrun0 = -INFINITY, lpart0 = 0.f;
  float mrun1 = -INFINITY, lpart1 = 0.f;
  f32x16 o0[4] = {}, o1[4] = {};

  // staging: inverse-swizzled global source -> linear LDS (rule 21)
#define STAGE_KV(kt_, bb)                                                                \
  {                                                                                      \
    const int kb0_ = kbase + (kt_) * 64;                                                 \
    _Pragma("unroll") for (int is = 0; is < 4; ++is) {                                   \
      int p = tid + is * 256;                                                            \
      int row = p >> 4, u = (p & 15) ^ (row & 15);                                       \
      GLOAD_LDS(Kf + (size_t)(b * SEQ + kb0_ + row) * LDK + h * HDIM + u * 8,            \
                KsB + (bb) * 16384 + p * 16);                                            \
    }                                                                                    \
    _Pragma("unroll") for (int is = 0; is < 4; ++is) {                                   \
      int p = tid + is * 256;                                                            \
      int row = p >> 4, u = (p & 15) ^ (row & 15);                                       \
      GLOAD_LDS(Vt + (size_t)(bh * HDIM + 2 * row + (u >> 3)) * SEQ + kb0_ +             \
                    (u & 7) * 8,                                                         \
                VsB + (bb) * 16384 + p * 16);                                            \
    }                                                                                    \
  }

  STAGE_KV(0, 0);
  __syncthreads();

  const int NT = 1024 / 64;                     // 16 tiles per key-half
  for (int kt = 0; kt < NT; ++kt) {
    const int cur = kt & 1;
    if (kt + 1 < NT) STAGE_KV(kt + 1, cur ^ 1);

#pragma unroll
    for (int kb = 0; kb < 2; ++kb) {
      const int kg = kh * 32 + kt * 2 + kb;
      // packed mask -> accumulator C-init for both q-groups
      bf16x8 mk00 = *(const bf16x8*)(mQ0 + (size_t)kg * 65536);
      bf16x8 mk01 = *(const bf16x8*)(mQ0 + (size_t)kg * 65536 + 8);
      bf16x8 mk10 = *(const bf16x8*)(mQ1 + (size_t)kg * 65536);
      bf16x8 mk11 = *(const bf16x8*)(mQ1 + (size_t)kg * 65536 + 8);
      f32x16 s0, s1;
#pragma unroll
      for (int r = 0; r < 8; ++r) {
        s0[r] = (float)mk00[r]; s0[8 + r] = (float)mk01[r];
        s1[r] = (float)mk10[r]; s1[8 + r] = (float)mk11[r];
      }

      // QK^T: K fragment read once, used by both q-groups
      const int krow = kb * 32 + q32;
      const int kx = krow & 15;
#pragma unroll
      for (int ds = 0; ds < 8; ++ds) {
        bf16x8 kfr = *(const bf16x8*)(KsB + cur * 16384 + krow * 256 +
                                      (((ds * 2 + hi) ^ kx) << 4));
        s0 = MFMA32(kfr, qf0[ds], s0);
        s1 = MFMA32(kfr, qf1[ds], s1);
      }

      // softmax + pack, q-group 0
      bf16x8 pav00, pav01, pav10, pav11;
      {
        float a0 = fmaxf(fmaxf(s0[0], s0[1]), fmaxf(s0[2], s0[3]));
        float a1 = fmaxf(fmaxf(s0[4], s0[5]), fmaxf(s0[6], s0[7]));
        float a2 = fmaxf(fmaxf(s0[8], s0[9]), fmaxf(s0[10], s0[11]));
        float a3 = fmaxf(fmaxf(s0[12], s0[13]), fmaxf(s0[14], s0[15]));
        float mx = fmaxf(fmaxf(a0, a1), fmaxf(a2, a3));
        mx = fmaxf(mx, __shfl_xor(mx, 32, 64));
        if (!__all(mx <= mrun0 + 8.f)) {
          float mnew = fmaxf(mrun0, mx);
          float corr = __expf(mrun0 - mnew);
          mrun0 = mnew; lpart0 *= corr;
#pragma unroll
          for (int d0 = 0; d0 < 4; ++d0)
#pragma unroll
            for (int r = 0; r < 16; ++r) o0[d0][r] *= corr;
        }
        float p_[16];
#pragma unroll
        for (int r = 0; r < 16; ++r) p_[r] = __expf(s0[r] - mrun0);
        float t0 = (p_[0] + p_[1]) + (p_[2] + p_[3]);
        float t1 = (p_[4] + p_[5]) + (p_[6] + p_[7]);
        float t2 = (p_[8] + p_[9]) + (p_[10] + p_[11]);
        float t3 = (p_[12] + p_[13]) + (p_[14] + p_[15]);
        lpart0 += (t0 + t1) + (t2 + t3);
        pav00 = pack_slice(p_, hi);
        pav01 = pack_slice(p_ + 8, hi);
      }
      // softmax + pack, q-group 1
      {
        float a0 = fmaxf(fmaxf(s1[0], s1[1]), fmaxf(s1[2], s1[3]));
        float a1 = fmaxf(fmaxf(s1[4], s1[5]), fmaxf(s1[6], s1[7]));
        float a2 = fmaxf(fmaxf(s1[8], s1[9]), fmaxf(s1[10], s1[11]));
        float a3 = fmaxf(fmaxf(s1[12], s1[13]), fmaxf(s1[14], s1[15]));
        float mx = fmaxf(fmaxf(a0, a1), fmaxf(a2, a3));
        mx = fmaxf(mx, __shfl_xor(mx, 32, 64));
        if (!__all(mx <= mrun1 + 8.f)) {
          float mnew = fmaxf(mrun1, mx);
          float corr = __expf(mrun1 - mnew);
          mrun1 = mnew; lpart1 *= corr;
#pragma unroll
          for (int d0 = 0; d0 < 4; ++d0)
#pragma unroll
            for (int r = 0; r < 16; ++r) o1[d0][r] *= corr;
        }
        float p_[16];
#pragma unroll
        for (int r = 0; r < 16; ++r) p_[r] = __expf(s1[r] - mrun1);
        float t0 = (p_[0] + p_[1]) + (p_[2] + p_[3]);
        float t1 = (p_[4] + p_[5]) + (p_[6] + p_[7]);
        float t2 = (p_[8] + p_[9]) + (p_[10] + p_[11]);
        float t3 = (p_[12] + p_[13]) + (p_[14] + p_[15]);
        lpart1 += (t0 + t1) + (t2 + t3);
        pav10 = pack_slice(p_, hi);
        pav11 = pack_slice(p_ + 8, hi);
      }

      // PV: V fragment read once (pair-interleaved tile), both q-groups
#pragma unroll
      for (int s = 0; s < 2; ++s) {
        const int gs = kb * 2 + s;
        bf16x8 pa0 = s ? pav01 : pav00;
        bf16x8 pa1 = s ? pav11 : pav10;
#pragma unroll
        for (int d0 = 0; d0 < 4; ++d0) {
          int vrow = d0 * 16 + (q32 >> 1);
          int slot = (((q32 & 1) << 3) + gs * 2 + hi) ^ (vrow & 15);
          bf16x8 vf = *(const bf16x8*)(VsB + cur * 16384 + vrow * 256 + slot * 16);
          o0[d0] = MFMA32(vf, pa0, o0[d0]);
          o1[d0] = MFMA32(vf, pa1, o1[d0]);
        }
      }
    }
    __syncthreads();
  }
#undef STAGE_KV

  // epilogue: store unnormalized partial O + (m, l)
  float l0 = lpart0 + __shfl_xor(lpart0, 32, 64);
  float l1 = lpart1 + __shfl_xor(lpart1, 32, 64);
  bf16_t* Op = kh ? Op1 : Op0;
  bf16_t* ao0 = Op + (size_t)(b * SEQ + qg0) * HID + h * HDIM;
  bf16_t* ao1 = ao0 + (size_t)32 * HID;
#pragma unroll
  for (int d0 = 0; d0 < 4; ++d0)
#pragma unroll
    for (int g = 0; g < 4; ++g) {
      int d = d0 * 32 + 8 * g + 4 * hi;
      unsigned lo0 = pk2(o0[d0][4 * g + 0], o0[d0][4 * g + 1]);
      unsigned hi0 = pk2(o0[d0][4 * g + 2], o0[d0][4 * g + 3]);
      *(unsigned*)(ao0 + d) = lo0;
      *(unsigned*)(ao0 + d + 2) = hi0;
      unsigned lo1 = pk2(o1[d0][4 * g + 0], o1[d0][4 * g + 1]);
      unsigned hi1 = pk2(o1[d0][4 * g + 2], o1[d0][4 * g + 3]);
      *(unsigned*)(ao1 + d) = lo1;
      *(unsigned*)(ao1 + d + 2) = hi1;
    }
  if (hi == 0) {
    float2* mlb = ml + ((size_t)(kh * 2 + b) * 16 + h) * 2048;
    float2 v0; v0.x = mrun0; v0.y = l0;
    float2 v1; v1.x = mrun1; v1.y = l1;
    mlb[qg0] = v0;
    mlb[qg0 + 32] = v1;
  }
}

// ---------------- combine: merge the two key-half partials into AO (in-place Op0) ---
__global__ void combine(const bf16_t* __restrict__ Op0, const bf16_t* __restrict__ Op1,
                        const float2* __restrict__ ml, bf16_t* __restrict__ AO) {
  int i8 = blockIdx.x * 256 + threadIdx.x;     // 1,048,576 chunks of 8 bf16
  int row = i8 >> 8;                           // b*S + q
  int h = (i8 >> 4) & 15;
  int b = row >> 11, q = row & 2047;
  float2 ml0 = ml[((size_t)b * 16 + h) * 2048 + q];
  float2 ml1 = ml[((size_t)(2 + b) * 16 + h) * 2048 + q];
  float m = fmaxf(ml0.x, ml1.x);
  float t0 = __expf(ml0.x - m), t1 = __expf(ml1.x - m);
  float rl = 1.f / (ml0.y * t0 + ml1.y * t1);
  float r0 = t0 * rl, r1 = t1 * rl;
  bf16x8 a = ((const bf16x8*)Op0)[i8];
  bf16x8 c = ((const bf16x8*)Op1)[i8];
  bf16x8 o;
#pragma unroll
  for (int j = 0; j < 8; ++j)
    o[j] = (bf16_t)((float)a[j] * r0 + (float)c[j] * r1);
  ((bf16x8*)AO)[i8] = o;
}

// ---------------- launch ----------------
extern "C" void kernel_launch(void* const* d_in, const int* in_sizes, int n_in,
                              void* d_out, int out_size, void* d_ws, size_t ws_size,
                              hipStream_t stream) {
  const float* hidden = (const float*)d_in[0];
  const float* cost   = (const float*)d_in[1];
  const float* sint   = (const float*)d_in[2];
  const float* mask   = (const float*)d_in[3];
  const float* Wq     = (const float*)d_in[4];
  const float* Wk     = (const float*)d_in[5];
  const float* Wv     = (const float*)d_in[6];
  const float* Wo     = (const float*)d_in[7];
  float* out = (float*)d_out;
  char* ws = (char*)d_ws;

  // layout (bytes), peak 117.4 MB:
  //   Af    @ 0           (dead after gemms) -> Vt aliases
  //   Op0   @ 16777216    (aliases dead Wq/Wk bf16; doubles as AO after combine)
  //   mlb   @ 33554432    (aliases dead Wvb; 1 MB)
  //   Wob   @ 41943040    live to end
  //   QK    @ 50331648    33.55 MB
  //   Vf    @ 83886080    (dead after transpose_v) -> maskP aliases
  //   Op1   @ 100663296   16.78 MB
  bf16_t* Af    = (bf16_t*)(ws + 0);
  bf16_t* Wqb   = (bf16_t*)(ws + 16777216);
  bf16_t* Wvb   = (bf16_t*)(ws + 33554432);
  bf16_t* Wob   = (bf16_t*)(ws + 41943040);
  bf16_t* QK    = (bf16_t*)(ws + 50331648);
  bf16_t* Vf    = (bf16_t*)(ws + 83886080);
  bf16_t* Vt    = (bf16_t*)(ws + 0);
  bf16_t* maskP = (bf16_t*)(ws + 83886080);
  bf16_t* Op0   = (bf16_t*)(ws + 16777216);
  bf16_t* Op1   = (bf16_t*)(ws + 100663296);
  float2* mlb   = (float2*)(ws + 33554432);
  bf16_t* AO    = Op0;

  cast_hidden<<<8192, 256, 0, stream>>>(hidden, Af);
  cast_weights<<<dim3(4096, 4), 256, 0, stream>>>(Wq, Wk, Wv, Wo, Wqb);

  // QK projection: A(4096x2048) * [Wq;Wk]^T (4096x2048) -> QK  (grid 256, no tail)
  gemm256<<<256, 512, 0, stream>>>(Af, Wqb, QK, nullptr, 4096, LDK, HID);
  // V projection: 128^2 tiles, 512 blocks fully resident
  gemm_bt<<<512, 256, 0, stream>>>(Af, Wvb, Vf, nullptr, 4096, HID, HID);

  rope_qk<<<2048, 256, 0, stream>>>(QK, cost, sint);
  transpose_v<<<dim3(64, 128), 256, 0, stream>>>(Vf, Vt);
  mask_pack<<<dim3(64, 64, 2), 256, 0, stream>>>(mask, maskP);

  flash_fwd<<<512, 256, 0, stream>>>(QK, QK + 2048, Vt, maskP, Op0, Op1, mlb);
  combine<<<4096, 256, 0, stream>>>(Op0, Op1, mlb, AO);

  gemm_bt<<<512, 256, 0, stream>>>(AO, Wob, nullptr, out, 4096, HID, HID);
}

// Round 10
// 318.768 us; speedup vs baseline: 1.3760x; 1.3760x over previous
//
#include <hip/hip_runtime.h>
#include <hip/hip_bf16.h>
#include <math.h>

// B=2, S=2048, H=2048, NH=16, HD=128
#define SEQ 2048
#define HID 2048
#define NHEAD 16
#define HDIM 128
#define LDK 4096   // fused QK row stride

typedef __bf16 bf16_t;
typedef __bf16 bf16x2 __attribute__((ext_vector_type(2)));
typedef __bf16 bf16x4_t __attribute__((ext_vector_type(4)));
typedef __bf16 bf16x8 __attribute__((ext_vector_type(8)));
typedef float f32x4 __attribute__((ext_vector_type(4)));
typedef float f32x16 __attribute__((ext_vector_type(16)));
typedef unsigned u32x4 __attribute__((ext_vector_type(4)));

#define MFMA16(a, b, c) __builtin_amdgcn_mfma_f32_16x16x32_bf16(a, b, c, 0, 0, 0)
#define MFMA32(a, b, c) __builtin_amdgcn_mfma_f32_32x32x16_bf16(a, b, c, 0, 0, 0)
#define GLOAD_LDS(g, l) \
  __builtin_amdgcn_global_load_lds((const __attribute__((address_space(1))) void*)(g), \
                                   (__attribute__((address_space(3))) void*)(l), 16, 0, 0)

static __device__ inline unsigned pk2(float lo, float hi) {
  bf16x2 t; t[0] = (bf16_t)lo; t[1] = (bf16_t)hi;
  return __builtin_bit_cast(unsigned, t);
}

// pack 8 p-values (one 16-key slice) into the PV B-fragment via cross-half exchange
static __device__ inline bf16x8 pack_slice(const float* p, int hi) {
  unsigned A1 = pk2(p[0], p[1]);
  unsigned A2 = pk2(p[2], p[3]);
  unsigned B1 = pk2(p[4], p[5]);
  unsigned B2 = pk2(p[6], p[7]);
  unsigned A1s = __shfl_xor(A1, 32, 64);
  unsigned A2s = __shfl_xor(A2, 32, 64);
  unsigned B1s = __shfl_xor(B1, 32, 64);
  unsigned B2s = __shfl_xor(B2, 32, 64);
  unsigned w0 = hi ? B1s : A1;
  unsigned w1 = hi ? B2s : A2;
  unsigned w2 = hi ? B1 : A1s;
  unsigned w3 = hi ? B2 : A2s;
  u32x4 W = {w0, w1, w2, w3};
  return __builtin_bit_cast(bf16x8, W);
}

// ---------------- cast kernels ----------------
__global__ void cast_hidden(const float* __restrict__ in, bf16_t* __restrict__ out) {
  int i = blockIdx.x * 256 + threadIdx.x;
  float4 v = ((const float4*)in)[i];
  bf16x4_t b;
  b[0] = (bf16_t)v.x; b[1] = (bf16_t)v.y; b[2] = (bf16_t)v.z; b[3] = (bf16_t)v.w;
  ((bf16x4_t*)out)[i] = b;
}

__global__ void cast_weights(const float* __restrict__ a, const float* __restrict__ b,
                             const float* __restrict__ c, const float* __restrict__ d,
                             bf16_t* __restrict__ out) {
  const float* srcs[4] = {a, b, c, d};
  const float* src = srcs[blockIdx.y];
  bf16_t* dst = out + (size_t)blockIdx.y * (HID * HID);
  int i = blockIdx.x * 256 + threadIdx.x;
  float4 v = ((const float4*)src)[i];
  bf16x4_t o;
  o[0] = (bf16_t)v.x; o[1] = (bf16_t)v.y; o[2] = (bf16_t)v.z; o[3] = (bf16_t)v.w;
  ((bf16x4_t*)dst)[i] = o;
}

// ---------------- 256x256 8-phase GEMM (grid MUST be 256 = 16x16 tiles) ----------
__global__ __launch_bounds__(512, 2) void gemm256(
    const bf16_t* __restrict__ A, const bf16_t* __restrict__ Bw,
    bf16_t* __restrict__ Cb, float* __restrict__ Cf, int M, int N, int K) {
  __shared__ char smem[131072];
  const int tid = threadIdx.x, lane = tid & 63, wid = tid >> 6;
  const int wr = wid >> 2, wc = wid & 3;
  const int lr = lane & 15, lg = lane >> 4;
  const int xcd = blockIdx.x & 7, l = blockIdx.x >> 3;
  const int brow = (xcd >> 2) * 8 + (l >> 2);
  const int bcol = (xcd & 3) * 4 + (l & 3);
  const int NT = K >> 6;

  const bf16_t* Ab = A + (size_t)(brow * 256) * K;
  const bf16_t* Bb = Bw + (size_t)(bcol * 256) * K;

  f32x4 acc[8][4] = {};
  bf16x8 af[4], bfr[4];
  const int swz = (lg ^ ((lr >> 1) & 3)) << 4;

#define STAGE_HALF(t_, op, kh)                                                        \
  {                                                                                   \
    int tt = (t_) < NT ? (t_) : NT - 1;                                               \
    const bf16_t* gsrc = (op) ? Bb : Ab;                                              \
    char* ldst = smem + (tt & 1) * 65536 + (op) * 32768 + (kh) * 16384;               \
    _Pragma("unroll") for (int is = 0; is < 2; ++is) {                                \
      int p = tid + is * 512;                                                         \
      int row = p >> 2, ch = p & 3;                                                   \
      GLOAD_LDS(gsrc + (size_t)row * K + tt * 64 + (kh) * 32 +                        \
                    ((ch ^ ((row >> 1) & 3)) * 8),                                    \
                ldst + p * 16);                                                       \
    }                                                                                 \
  }

#define PHASE(cb, kh, mh, LOADB, STAGECALL, VM)                                       \
  {                                                                                   \
    _Pragma("unroll") for (int mf = 0; mf < 4; ++mf) {                                \
      int row = wr * 128 + (mh) * 64 + mf * 16 + lr;                                  \
      af[mf] = *(const bf16x8*)(smem + (cb) * 65536 + (kh) * 16384 + row * 64 + swz); \
    }                                                                                 \
    if (LOADB) {                                                                      \
      _Pragma("unroll") for (int nf = 0; nf < 4; ++nf) {                              \
        int row = wc * 64 + nf * 16 + lr;                                             \
        bfr[nf] = *(const bf16x8*)(smem + (cb) * 65536 + 32768 + (kh) * 16384 +       \
                                   row * 64 + swz);                                   \
      }                                                                               \
    }                                                                                 \
    STAGECALL;                                                                        \
    __builtin_amdgcn_s_barrier();                                                     \
    asm volatile("s_waitcnt lgkmcnt(0)" ::: "memory");                                \
    __builtin_amdgcn_sched_barrier(0);                                                \
    __builtin_amdgcn_s_setprio(1);                                                    \
    _Pragma("unroll") for (int mf = 0; mf < 4; ++mf)                                  \
      _Pragma("unroll") for (int nf = 0; nf < 4; ++nf)                                \
        acc[(mh) * 4 + mf][nf] = MFMA16(af[mf], bfr[nf], acc[(mh) * 4 + mf][nf]);     \
    __builtin_amdgcn_s_setprio(0);                                                    \
    if (VM) { asm volatile("s_waitcnt vmcnt(6)" ::: "memory"); }                      \
    __builtin_amdgcn_s_barrier();                                                     \
    __builtin_amdgcn_sched_barrier(0);                                                \
  }

  STAGE_HALF(0, 1, 0); STAGE_HALF(0, 0, 0); STAGE_HALF(0, 1, 1); STAGE_HALF(0, 0, 1);
  STAGE_HALF(1, 1, 0); STAGE_HALF(1, 0, 0); STAGE_HALF(1, 1, 1);
  asm volatile("s_waitcnt vmcnt(6)" ::: "memory");
  __builtin_amdgcn_s_barrier();
  __builtin_amdgcn_sched_barrier(0);

  const int NI = NT >> 1;
  for (int i = 0; i < NI; ++i) {
    const int t2 = 2 * i;
    PHASE(0, 0, 0, 1, STAGE_HALF(t2 + 1, 0, 1), 0);
    PHASE(0, 0, 1, 0, STAGE_HALF(t2 + 2, 1, 0), 0);
    PHASE(0, 1, 0, 1, STAGE_HALF(t2 + 2, 0, 0), 0);
    PHASE(0, 1, 1, 0, STAGE_HALF(t2 + 2, 1, 1), 1);
    PHASE(1, 0, 0, 1, STAGE_HALF(t2 + 2, 0, 1), 0);
    PHASE(1, 0, 1, 0, STAGE_HALF(t2 + 3, 1, 0), 0);
    PHASE(1, 1, 0, 1, STAGE_HALF(t2 + 3, 0, 0), 0);
    PHASE(1, 1, 1, 0, STAGE_HALF(t2 + 3, 1, 1), 1);
  }
#undef PHASE
#undef STAGE_HALF

#pragma unroll
  for (int mi = 0; mi < 8; ++mi)
#pragma unroll
    for (int nf = 0; nf < 4; ++nf)
#pragma unroll
      for (int r = 0; r < 4; ++r) {
        int row = brow * 256 + wr * 128 + (mi >> 2) * 64 + (mi & 3) * 16 + lg * 4 + r;
        int col = bcol * 256 + wc * 64 + nf * 16 + lr;
        float v = acc[mi][nf][r];
        if (Cf) Cf[(size_t)row * N + col] = v;
        else    Cb[(size_t)row * N + col] = (bf16_t)v;
      }
}

// ---------------- GEMM: C = A * B^T, 2-phase double-buffered (128x128) -------------
__global__ __launch_bounds__(256, 3) void gemm_bt(
    const bf16_t* __restrict__ A, const bf16_t* __restrict__ Bw,
    bf16_t* __restrict__ Cb, float* __restrict__ Cf,
    int M, int N, int K) {
  __shared__ bf16_t As[2][128 * 32];
  __shared__ bf16_t Bs[2][128 * 32];
  const int tid = threadIdx.x;
  const int lane = tid & 63, wid = tid >> 6;
  const int wr = wid >> 1, wc = wid & 1;
  const int lr = lane & 15, lg = lane >> 4;
  const int nwg = gridDim.x;
  const int lid = (blockIdx.x & 7) * (nwg >> 3) + (blockIdx.x >> 3);
  const int nbc = N >> 7;
  const int brow = lid / nbc, bcol = lid % nbc;

  f32x4 acc[4][4] = {};
  const int swz = lg ^ ((lr >> 1) & 3);

  const int srow = tid >> 2, sch = tid & 3;
#define GSTAGE(k0, bb)                                                                   \
  {                                                                                      \
    _Pragma("unroll") for (int is = 0; is < 2; ++is) {                                   \
      int row = srow + is * 64;                                                          \
      int g = (sch ^ ((row >> 1) & 3)) * 8;                                              \
      GLOAD_LDS(A + (size_t)(brow * 128 + row) * K + (k0) + g,                           \
                &As[bb][(row * 4 + sch) * 8]);                                           \
      GLOAD_LDS(Bw + (size_t)(bcol * 128 + row) * K + (k0) + g,                          \
                &Bs[bb][(row * 4 + sch) * 8]);                                           \
    }                                                                                    \
  }

  GSTAGE(0, 0);
  __syncthreads();

  const int nt = K / 32;
  for (int t = 0; t < nt; ++t) {
    const int cb = t & 1;
    if (t + 1 < nt) GSTAGE((t + 1) * 32, cb ^ 1);
    bf16x8 af[4], bfr[4];
#pragma unroll
    for (int m = 0; m < 4; ++m)
      af[m] = *(const bf16x8*)(&As[cb][(wr * 64 + m * 16 + lr) * 32 + swz * 8]);
#pragma unroll
    for (int n = 0; n < 4; ++n)
      bfr[n] = *(const bf16x8*)(&Bs[cb][(wc * 64 + n * 16 + lr) * 32 + swz * 8]);
#pragma unroll
    for (int m = 0; m < 4; ++m)
#pragma unroll
      for (int n = 0; n < 4; ++n)
        acc[m][n] = MFMA16(af[m], bfr[n], acc[m][n]);
    __syncthreads();
  }
#undef GSTAGE

#pragma unroll
  for (int m = 0; m < 4; ++m)
#pragma unroll
    for (int n = 0; n < 4; ++n)
#pragma unroll
      for (int r = 0; r < 4; ++r) {
        int row = brow * 128 + wr * 64 + m * 16 + lg * 4 + r;
        int col = bcol * 128 + wc * 64 + n * 16 + lr;
        float v = acc[m][n][r];
        if (Cf) Cf[(size_t)row * N + col] = v;
        else    Cb[(size_t)row * N + col] = (bf16_t)v;
      }
}

// ---------------- RoPE in-place on QK buffer (stride LDK); Q pre-scaled ----------
__global__ void rope_qk(bf16_t* __restrict__ QK,
                        const float* __restrict__ cost, const float* __restrict__ sint) {
  const float SCALE = 0.08838834764831845f;  // 1/sqrt(128)
  int idx = blockIdx.x * 256 + threadIdx.x;
  int d8 = idx & 7;
  int t = idx >> 3;
  int h = t & 15;
  int row = t >> 4;
  int s = row & (SEQ - 1);
  size_t base = (size_t)row * LDK + h * HDIM;
  const float4* cp = (const float4*)(cost + s * HDIM);
  const float4* sp = (const float4*)(sint + s * HDIM);
  float4 c0a = cp[d8 * 2], c0b = cp[d8 * 2 + 1];
  float4 c1a = cp[16 + d8 * 2], c1b = cp[16 + d8 * 2 + 1];
  float4 s0a = sp[d8 * 2], s0b = sp[d8 * 2 + 1];
  float4 s1a = sp[16 + d8 * 2], s1b = sp[16 + d8 * 2 + 1];
  float c0[8] = {c0a.x, c0a.y, c0a.z, c0a.w, c0b.x, c0b.y, c0b.z, c0b.w};
  float c1[8] = {c1a.x, c1a.y, c1a.z, c1a.w, c1b.x, c1b.y, c1b.z, c1b.w};
  float s0[8] = {s0a.x, s0a.y, s0a.z, s0a.w, s0b.x, s0b.y, s0b.z, s0b.w};
  float s1[8] = {s1a.x, s1a.y, s1a.z, s1a.w, s1b.x, s1b.y, s1b.z, s1b.w};

  bf16_t* Q = QK;
  bf16_t* K = QK + 2048;
  bf16x8 qlo = *(bf16x8*)(Q + base + d8 * 8);
  bf16x8 qhi = *(bf16x8*)(Q + base + 64 + d8 * 8);
  bf16x8 klo = *(bf16x8*)(K + base + d8 * 8);
  bf16x8 khi = *(bf16x8*)(K + base + 64 + d8 * 8);
  bf16x8 qlo2, qhi2, klo2, khi2;
#pragma unroll
  for (int j = 0; j < 8; ++j) {
    float q0 = (float)qlo[j], q1 = (float)qhi[j];
    qlo2[j] = (bf16_t)((q0 * c0[j] - q1 * s0[j]) * SCALE);
    qhi2[j] = (bf16_t)((q1 * c1[j] + q0 * s1[j]) * SCALE);
    float k0 = (float)klo[j], k1 = (float)khi[j];
    klo2[j] = (bf16_t)(k0 * c0[j] - k1 * s0[j]);
    khi2[j] = (bf16_t)(k1 * c1[j] + k0 * s1[j]);
  }
  *(bf16x8*)(Q + base + d8 * 8) = qlo2;
  *(bf16x8*)(Q + base + 64 + d8 * 8) = qhi2;
  *(bf16x8*)(K + base + d8 * 8) = klo2;
  *(bf16x8*)(K + base + 64 + d8 * 8) = khi2;
}

// ---------------- V transpose: Vf (B*S x H) -> Vt[b][h][d][s] ----------------
__global__ void transpose_v(const bf16_t* __restrict__ Vf, bf16_t* __restrict__ Vt) {
  __shared__ bf16_t t[32][33];
  int tx = threadIdx.x & 31, ty = threadIdx.x >> 5;
  int r0 = blockIdx.y * 32, c0 = blockIdx.x * 32;
#pragma unroll
  for (int j = 0; j < 4; ++j)
    t[ty + j * 8][tx] = Vf[(size_t)(r0 + ty + j * 8) * HID + c0 + tx];
  __syncthreads();
#pragma unroll
  for (int j = 0; j < 4; ++j) {
    int c = c0 + ty + j * 8;
    int r = r0 + tx;
    int h = c >> 7, d = c & 127, b = r >> 11, s = r & (SEQ - 1);
    Vt[(((size_t)(b * NHEAD + h)) * HDIM + d) * SEQ + s] = t[tx][ty + j * 8];
  }
}

// ---------------- mask pack: mask[b][0][q][k] f32 -> maskP[b][kg][q][kl'] bf16 ------
__global__ void mask_pack(const float* __restrict__ m, bf16_t* __restrict__ mp) {
  __shared__ float t[32][33];
  int tx = threadIdx.x & 31, ty = threadIdx.x >> 5;
  int q0 = blockIdx.x * 32, k0 = blockIdx.y * 32;
  const float* mb = m + (size_t)blockIdx.z * SEQ * SEQ;
#pragma unroll
  for (int j = 0; j < 4; ++j)
    t[ty + j * 8][tx] = mb[(size_t)(q0 + ty + j * 8) * SEQ + k0 + tx];
  __syncthreads();
  int r = tx & 15, hi = tx >> 4;
  int kl = (r & 3) + 8 * (r >> 2) + 4 * hi;
  bf16_t* ob = mp + ((size_t)(blockIdx.z * 64 + blockIdx.y) * 2048 + q0) * 32;
#pragma unroll
  for (int j = 0; j < 4; ++j) {
    int qloc = ty + j * 8;
    ob[(size_t)qloc * 32 + tx] = (bf16_t)t[qloc][kl];
  }
}

// ---------------- flash attention fwd v5: 8 waves x 32q, KVBLK=128, conflict-free ---
// grid 256 = 8 qt x 32 bh (bh in low bits -> 4 bh per XCD, K/V L2-resident).
// 512 thr = 8 waves x 32 q = 256 q/block; KVBLK=128 double-buffered (128 KB LDS,
// 1 block/CU but 8 waves/CU = 2/SIMD). K [128 keys][256B], V [128 d][256B],
// slot XOR (row&15) -> 0 bank conflicts (verified R8/R9). One stage feeds 8 waves.
__global__ __launch_bounds__(512, 2) void flash_fwd(
    const bf16_t* __restrict__ Qf, const bf16_t* __restrict__ Kf,
    const bf16_t* __restrict__ Vt, const bf16_t* __restrict__ maskP,
    bf16_t* __restrict__ AO) {
  __shared__ char smem[131072];          // K 2x32K | V 2x32K
  char* KsB = smem;
  char* VsB = smem + 65536;
  const int tid = threadIdx.x, lane = tid & 63, wid = tid >> 6;
  const int q32 = lane & 31, hi = lane >> 5;

  const int x = blockIdx.x;
  const int bh = x & 31, qt = x >> 5;          // qt 0..7
  const int b = bh >> 4, h = bh & 15;
  const int qg = qt * 256 + wid * 32 + q32;

  // Q fragments (B-operand): lane holds Q[q][d = ds*16 + hi*8 + j]
  bf16x8 qf[8];
  const bf16_t* qptr = Qf + (size_t)(b * SEQ + qg) * LDK + h * HDIM + hi * 8;
#pragma unroll
  for (int ds = 0; ds < 8; ++ds) qf[ds] = *(const bf16x8*)(qptr + ds * 16);

  // packed mask base for this lane
  const bf16_t* mQ = maskP + (size_t)b * 64 * 65536 + (size_t)qg * 32 + hi * 16;

  float mrun = -INFINITY, lpart = 0.f;
  f32x16 o[4] = {};

#define STAGE_KV(kt_, bb)                                                                \
  {                                                                                      \
    const int kb0_ = (kt_) * 128;                                                        \
    _Pragma("unroll") for (int is = 0; is < 4; ++is) {                                   \
      int p = tid + is * 512;                                                            \
      int row = p >> 4, ch = p & 15;                                                     \
      int src = (ch * 16) ^ ((row & 15) << 4);                                           \
      GLOAD_LDS((const char*)(Kf + (size_t)(b * SEQ + kb0_ + row) * LDK + h * HDIM) +    \
                    src,                                                                 \
                KsB + (bb) * 32768 + p * 16);                                            \
      GLOAD_LDS((const char*)(Vt + (size_t)(bh * HDIM + row) * SEQ + kb0_) + src,        \
                VsB + (bb) * 32768 + p * 16);                                            \
    }                                                                                    \
  }

  STAGE_KV(0, 0);
  __syncthreads();

  const int NT = SEQ / 128;                     // 16
  for (int kt = 0; kt < NT; ++kt) {
    const int cur = kt & 1;
    if (kt + 1 < NT) STAGE_KV(kt + 1, cur ^ 1);

#pragma unroll
    for (int kb = 0; kb < 4; ++kb) {
      const int kg = kt * 4 + kb;
      // packed mask -> accumulator C-init (free mask add)
      bf16x8 mk0 = *(const bf16x8*)(mQ + (size_t)kg * 65536);
      bf16x8 mk1 = *(const bf16x8*)(mQ + (size_t)kg * 65536 + 8);
      f32x16 sacc;
#pragma unroll
      for (int r = 0; r < 8; ++r) {
        sacc[r] = (float)mk0[r];
        sacc[8 + r] = (float)mk1[r];
      }

      // QK^T: A = K frag from LDS (row=key, k=d)
      const int krow = kb * 32 + q32;
      const int kswz = (krow & 15) << 4;
#pragma unroll
      for (int ds = 0; ds < 8; ++ds) {
        bf16x8 kfr = *(const bf16x8*)(KsB + cur * 32768 + krow * 256 +
                                      ((ds * 32 + hi * 16) ^ kswz));
        sacc = MFMA32(kfr, qf[ds], sacc);
      }

      // row max (pairwise tree) + cross-half combine
      float a0 = fmaxf(fmaxf(sacc[0], sacc[1]), fmaxf(sacc[2], sacc[3]));
      float a1 = fmaxf(fmaxf(sacc[4], sacc[5]), fmaxf(sacc[6], sacc[7]));
      float a2 = fmaxf(fmaxf(sacc[8], sacc[9]), fmaxf(sacc[10], sacc[11]));
      float a3 = fmaxf(fmaxf(sacc[12], sacc[13]), fmaxf(sacc[14], sacc[15]));
      float mx = fmaxf(fmaxf(a0, a1), fmaxf(a2, a3));
      mx = fmaxf(mx, __shfl_xor(mx, 32, 64));
      // defer-max (T13)
      if (!__all(mx <= mrun + 8.f)) {
        float mnew = fmaxf(mrun, mx);
        float corr = __expf(mrun - mnew);
        mrun = mnew; lpart *= corr;
#pragma unroll
        for (int d0 = 0; d0 < 4; ++d0)
#pragma unroll
          for (int r = 0; r < 16; ++r) o[d0][r] *= corr;
      }

      // P = exp(s - m); pairwise-tree partial row sum
      float p_[16];
#pragma unroll
      for (int r = 0; r < 16; ++r) p_[r] = __expf(sacc[r] - mrun);
      {
        float t0 = (p_[0] + p_[1]) + (p_[2] + p_[3]);
        float t1 = (p_[4] + p_[5]) + (p_[6] + p_[7]);
        float t2 = (p_[8] + p_[9]) + (p_[10] + p_[11]);
        float t3 = (p_[12] + p_[13]) + (p_[14] + p_[15]);
        lpart += (t0 + t1) + (t2 + t3);
      }

      // re-layout P and run PV for this 32-key group
#pragma unroll
      for (int s = 0; s < 2; ++s) {
        bf16x8 pav = pack_slice(p_ + 8 * s, hi);
        const int gs = kb * 2 + s;              // 16-key slice in the 128-key tile
#pragma unroll
        for (int d0 = 0; d0 < 4; ++d0) {
          int vrow = d0 * 32 + q32;
          bf16x8 vf = *(const bf16x8*)(VsB + cur * 32768 + vrow * 256 +
                                       ((gs * 32 + hi * 16) ^ ((vrow & 15) << 4)));
          o[d0] = MFMA32(vf, pav, o[d0]);
        }
      }
    }
    __syncthreads();
  }
#undef STAGE_KV

  // epilogue: full row sum, normalize, write AO
  float l = lpart + __shfl_xor(lpart, 32, 64);
  float rl = 1.f / l;
  bf16_t* aorow = AO + (size_t)(b * SEQ + qg) * HID + h * HDIM;
#pragma unroll
  for (int d0 = 0; d0 < 4; ++d0)
#pragma unroll
    for (int g = 0; g < 4; ++g) {
      unsigned lo = pk2(o[d0][4 * g + 0] * rl, o[d0][4 * g + 1] * rl);
      unsigned hi2 = pk2(o[d0][4 * g + 2] * rl, o[d0][4 * g + 3] * rl);
      int d = d0 * 32 + 8 * g + 4 * hi;
      *(unsigned*)(aorow + d) = lo;
      *(unsigned*)(aorow + d + 2) = hi2;
    }
}

// ---------------- launch ----------------
extern "C" void kernel_launch(void* const* d_in, const int* in_sizes, int n_in,
                              void* d_out, int out_size, void* d_ws, size_t ws_size,
                              hipStream_t stream) {
  const float* hidden = (const float*)d_in[0];
  const float* cost   = (const float*)d_in[1];
  const float* sint   = (const float*)d_in[2];
  const float* mask   = (const float*)d_in[3];
  const float* Wq     = (const float*)d_in[4];
  const float* Wk     = (const float*)d_in[5];
  const float* Wv     = (const float*)d_in[6];
  const float* Wo     = (const float*)d_in[7];
  float* out = (float*)d_out;
  char* ws = (char*)d_ws;

  // layout (bytes), peak 100.66 MB:
  //   Af    @ 0          (dead after gemms) -> Vt aliases
  //   AO    @ 16777216   (aliases dead Wq/Wk bf16 copies)
  //   Wvb   @ 33554432   ; Wob @ 41943040 (live to end)
  //   QK    @ 50331648   33.55 MB
  //   Vf    @ 83886080   (dead after transpose_v) -> maskP aliases
  bf16_t* Af    = (bf16_t*)(ws + 0);
  bf16_t* Wqb   = (bf16_t*)(ws + 16777216);
  bf16_t* Wvb   = (bf16_t*)(ws + 33554432);
  bf16_t* Wob   = (bf16_t*)(ws + 41943040);
  bf16_t* QK    = (bf16_t*)(ws + 50331648);
  bf16_t* Vf    = (bf16_t*)(ws + 83886080);
  bf16_t* Vt    = (bf16_t*)(ws + 0);
  bf16_t* maskP = (bf16_t*)(ws + 83886080);
  bf16_t* AO    = (bf16_t*)(ws + 16777216);

  cast_hidden<<<8192, 256, 0, stream>>>(hidden, Af);
  cast_weights<<<dim3(4096, 4), 256, 0, stream>>>(Wq, Wk, Wv, Wo, Wqb);

  // QK projection: A(4096x2048) * [Wq;Wk]^T (4096x2048) -> QK  (grid 256, no tail)
  gemm256<<<256, 512, 0, stream>>>(Af, Wqb, QK, nullptr, 4096, LDK, HID);
  // V projection: 128^2 tiles, 512 blocks fully resident
  gemm_bt<<<512, 256, 0, stream>>>(Af, Wvb, Vf, nullptr, 4096, HID, HID);

  rope_qk<<<2048, 256, 0, stream>>>(QK, cost, sint);
  transpose_v<<<dim3(64, 128), 256, 0, stream>>>(Vf, Vt);
  mask_pack<<<dim3(64, 64, 2), 256, 0, stream>>>(mask, maskP);

  flash_fwd<<<256, 512, 0, stream>>>(QK, QK + 2048, Vt, maskP, AO);

  gemm_bt<<<512, 256, 0, stream>>>(AO, Wob, nullptr, out, 4096, HID, HID);
}